// Round 5
// baseline (154.906 us; speedup 1.0000x reference)
//
#include <hip/hip_runtime.h>

#define NB 8
#define SS 2048
#define HH 512
#define NSTY 128
#define SP (SS + 2)
#define EPSF 1e-5f

#define BM 256
#define BN 128
#define BK 64

typedef __attribute__((ext_vector_type(8))) short short8;
typedef __attribute__((ext_vector_type(4))) float floatx4;
typedef __attribute__((ext_vector_type(4))) unsigned short u16x4;
typedef unsigned short u16;

__device__ __forceinline__ float bf2f(u16 u) {
  union { float f; unsigned int i; } v; v.i = ((unsigned int)u) << 16; return v.f;
}
__device__ __forceinline__ u16 f2bf(float f) {
  union { float f; unsigned int i; } v; v.f = f;
  unsigned int x = v.i;
  return (u16)((x + 0x7fffu + ((x >> 16) & 1u)) >> 16);
}
__device__ __forceinline__ float lrelu(float v) { return v >= 0.f ? v : 0.2f * v; }

__device__ __forceinline__ void gld_lds16(const u16* g, u16* l) {
  __builtin_amdgcn_global_load_lds((const __attribute__((address_space(1))) void*)g,
                                   (__attribute__((address_space(3))) void*)l, 16, 0, 0);
}

// ---------------- zero stats ----------------
__global__ void k_zero(float* p, int n) {
  int i = blockIdx.x * 256 + threadIdx.x;
  if (i < n) p[i] = 0.f;
}

// ---------------- style projections (both) ----------------
__global__ void k_proj(const float* style, const float* w1, const float* b1,
                       const float* w2, const float* b2,
                       float* g1, float* be1, float* g2, float* be2) {
  int idx = blockIdx.x * 256 + threadIdx.x;         // 2 * NB * 2H
  if (idx >= 2 * NB * 2 * HH) return;
  int which = idx / (NB * 2 * HH);
  int r = idx % (NB * 2 * HH);
  int b = r / (2 * HH);
  int j = r % (2 * HH);
  const float* w = which ? w2 : w1;
  const float* bias = which ? b2 : b1;
  float acc = bias[j];
  const float* st = style + b * NSTY;
  const float* wr = w + j * NSTY;
  for (int t = 0; t < NSTY; t++) acc += st[t] * wr[t];
  float* gd = which ? g2 : g1;
  float* bd = which ? be2 : be1;
  if (j < HH) gd[b * HH + j] = acc;
  else        bd[b * HH + (j - HH)] = acc;
}

// ---------------- weight norm + repack to bf16 [k][o][i] ----------------
__global__ void k_wnorm(const float* v1, const float* g1, const float* v2, const float* g2,
                        u16* wt1, u16* wt2) {
  int o = blockIdx.x % HH;
  int which = blockIdx.x / HH;
  const float* v = which ? v2 : v1;
  const float* g = which ? g2 : g1;
  u16* wt = which ? wt2 : wt1;
  float s = 0.f;
  for (int e = threadIdx.x; e < HH * 3; e += 256) {
    float x = v[o * HH * 3 + e];
    s += x * x;
  }
  for (int off = 32; off > 0; off >>= 1) s += __shfl_down(s, off, 64);
  __shared__ float red[4];
  int wid = threadIdx.x >> 6, lane = threadIdx.x & 63;
  if (lane == 0) red[wid] = s;
  __syncthreads();
  float tot = red[0] + red[1] + red[2] + red[3];
  float scale = g[o] / sqrtf(tot);
  for (int e = threadIdx.x; e < HH * 3; e += 256) {
    int i = e / 3, k = e % 3;      // v[o][i][k] flat = o*1536 + e
    wt[(k * HH + o) * HH + i] = f2bf(v[o * HH * 3 + e] * scale);
  }
}

// ---------------- masked stats over S (f32 input) ----------------
__global__ void k_stats_f32(const float* x, const int* lens, float* sum, float* sumsq) {
  const int SSPLIT = 16;
  int t = blockIdx.x;
  int sc = t % SSPLIT; t /= SSPLIT;
  int ht = t % (HH / 256); t /= (HH / 256);
  int b = t;
  int h = ht * 256 + threadIdx.x;
  int len = lens[b];
  int s0 = sc * (SS / SSPLIT);
  int se = min(s0 + SS / SSPLIT, len);
  float sm = 0.f, sq = 0.f;
  for (int s = s0; s < se; s++) {
    float v = x[(b * SS + s) * HH + h];
    sm += v; sq += v * v;
  }
  if (se > s0) {
    atomicAdd(&sum[b * HH + h], sm);
    atomicAdd(&sumsq[b * HH + h], sq);
  }
}

// ---------------- finalize adain affine ----------------
__global__ void k_fin(const float* sum, const float* sumsq, const int* lens,
                      const float* gam, const float* bet, float* a, float* c) {
  int idx = blockIdx.x * 256 + threadIdx.x;   // NB*HH
  if (idx >= NB * HH) return;
  int b = idx / HH;
  float cnt = (float)lens[b];
  float mean = sum[idx] / cnt;
  float var = sumsq[idx] / cnt - mean * mean;
  float rs = rsqrtf(var + EPSF);
  float av = (1.f + gam[idx]) * rs;
  a[idx] = av;
  c[idx] = bet[idx] - mean * av;
}

// ---------------- Z prep (f32 src) ----------------
__global__ void k_prep_f32(const float* x, const float* a, const float* c,
                           const int* lens, u16* z) {
  int tid = blockIdx.x * 256 + threadIdx.x;
  long idx = (long)tid * 4;
  if (idx >= (long)NB * SP * HH) return;
  int i = (int)(idx % HH);
  long rs_ = idx / HH;
  int r = (int)(rs_ % SP);
  int b = (int)(rs_ / SP);
  int s = r - 1;
  u16x4 outv;
  if (s < 0 || s >= SS || s >= lens[b]) {
    outv = (u16x4){0, 0, 0, 0};
  } else {
    const float4 xv = *(const float4*)(x + ((long)(b * SS + s)) * HH + i);
    const float4 av = *(const float4*)(a + b * HH + i);
    const float4 cv = *(const float4*)(c + b * HH + i);
    outv.x = f2bf(lrelu(av.x * xv.x + cv.x));
    outv.y = f2bf(lrelu(av.y * xv.y + cv.y));
    outv.z = f2bf(lrelu(av.z * xv.z + cv.z));
    outv.w = f2bf(lrelu(av.w * xv.w + cv.w));
  }
  *(u16x4*)(z + ((long)(b * SP + r)) * HH + i) = outv;
}

// ---------------- Z prep (bf16 src) ----------------
__global__ void k_prep_bf16(const u16* y, const float* a, const float* c,
                            const int* lens, u16* z) {
  int tid = blockIdx.x * 256 + threadIdx.x;
  long idx = (long)tid * 4;
  if (idx >= (long)NB * SP * HH) return;
  int i = (int)(idx % HH);
  long rs_ = idx / HH;
  int r = (int)(rs_ % SP);
  int b = (int)(rs_ / SP);
  int s = r - 1;
  u16x4 outv;
  if (s < 0 || s >= SS || s >= lens[b]) {
    outv = (u16x4){0, 0, 0, 0};
  } else {
    const u16x4 yv = *(const u16x4*)(y + ((long)(b * SS + s)) * HH + i);
    const float4 av = *(const float4*)(a + b * HH + i);
    const float4 cv = *(const float4*)(c + b * HH + i);
    outv.x = f2bf(lrelu(av.x * bf2f(yv.x) + cv.x));
    outv.y = f2bf(lrelu(av.y * bf2f(yv.y) + cv.y));
    outv.z = f2bf(lrelu(av.z * bf2f(yv.z) + cv.z));
    outv.w = f2bf(lrelu(av.w * bf2f(yv.w) + cv.w));
  }
  *(u16x4*)(z + ((long)(b * SP + r)) * HH + i) = outv;
}

// ---------------- conv1d as flat GEMM, m201-style fine-interleaved phases ----
// Flat identity: z[b][s+k][i] = zflat[s*HH + (k*HH+i)] -> GEMM rows at stride
// HH, K = 3*HH contiguous. BM=256 BN=128 BK=64, 512 threads (8 waves, 4Mx2N,
// wave tile 64x64, acc 4x4). 3-buffer named-LDS ring (144 KB), grid 256 =
// 1 block/CU. Per K-tile: TWO phases, each
//   {8 ds_read (one kk slice) | 3 global_load_lds (tile t+2 chunk) |
//    s_barrier | lgkmcnt(0)+sched_barrier | setprio(1) 16 MFMA setprio(0) |
//    s_barrier}
// vmcnt(6) ONLY at the K-tile boundary (tile t+1 landed, t+2 in flight) —
// the m196/m201 fine interleave; coarse variants measured -7..-27%.
// Ring unrolled as triples so each call site has compile-time-distinct
// buffers (no LDS-DMA alias conservatism). XOR involution swizzle on both
// global source col and ds_read addr. XCD remap: one batch per XCD.
__global__ __launch_bounds__(512) void k_conv(const u16* __restrict__ z,
                                              const u16* __restrict__ wt,
                                              const float* __restrict__ bias,
                                              const int* __restrict__ lens,
                                              u16* __restrict__ yout,
                                              const float* __restrict__ resid,
                                              float* __restrict__ fout,
                                              float* __restrict__ sum,
                                              float* __restrict__ sumsq) {
  __shared__ __align__(16) u16 LA0[BM * BK];
  __shared__ __align__(16) u16 LA1[BM * BK];
  __shared__ __align__(16) u16 LA2[BM * BK];
  __shared__ __align__(16) u16 LB0[BN * BK];
  __shared__ __align__(16) u16 LB1[BN * BK];
  __shared__ __align__(16) u16 LB2[BN * BK];

  int nwg = gridDim.x;                        // 256, divisible by 8
  int bid = blockIdx.x;
  int t = (bid & 7) * (nwg >> 3) + (bid >> 3);     // XCD-contiguous logical id
  int bn0 = (t % (HH / BN)) * BN; t /= (HH / BN);
  int bm0 = (t % (SS / BM)) * BM; t /= (SS / BM);
  int b = t;

  int tid = threadIdx.x;
  int wave = tid >> 6, lane = tid & 63;
  int wr = wave >> 1, wc = wave & 1;          // 4 M-waves x 2 N-waves
  int l15 = lane & 15, l4 = lane >> 4;

  const u16* zb = z + (size_t)b * SP * HH;
  int trow = tid >> 3;                        // 0..63
  int tslot = tid & 7;                        // 16B slot within 128B row

  int len = lens[b];                          // scalar load, before pipeline

  floatx4 acc[4][4] = {};

  // --- staging helpers: LDS dest linear in tid (wave-uniform base + lane*16B),
  // global source column pre-swizzled by the involution slot^(row&7) ---
  auto stageA2 = [&](u16* dA, int kt, int rr0) {   // 2 A-rows-groups
    int k0 = kt * BK;
#pragma unroll
    for (int rr = rr0; rr < rr0 + 2; rr++) {
      int r = rr * 64 + trow;
      int sc = (tslot ^ (r & 7)) * 8;
      gld_lds16(zb + (size_t)(bm0 + r) * HH + k0 + sc, dA + rr * 4096 + tid * 8);
    }
  };
  auto stageB1 = [&](u16* dB, int kt, int rr) {    // 1 B-rows-group
    int k0 = kt * BK;
    const u16* wkb = wt + (size_t)(k0 >> 9) * HH * HH + (k0 & 511);
    int r = rr * 64 + trow;
    int sc = (tslot ^ (r & 7)) * 8;
    gld_lds16(wkb + (size_t)(bn0 + r) * HH + sc, dB + rr * 4096 + tid * 8);
  };

  auto dsread = [&](const u16* sA, const u16* sB, int kk, short8* afr, short8* bfr) {
#pragma unroll
    for (int i = 0; i < 4; i++) {
      int ar = wr * 64 + i * 16 + l15;
      afr[i] = *(const short8*)&sA[ar * BK + (((kk * 4 + l4) ^ (ar & 7)) * 8)];
    }
#pragma unroll
    for (int j = 0; j < 4; j++) {
      int br = wc * 64 + j * 16 + l15;
      bfr[j] = *(const short8*)&sB[br * BK + (((kk * 4 + l4) ^ (br & 7)) * 8)];
    }
  };
  auto mfma16 = [&](short8* afr, short8* bfr) {
    __builtin_amdgcn_s_setprio(1);
#pragma unroll
    for (int am = 0; am < 4; am++)
#pragma unroll
      for (int bn = 0; bn < 4; bn++)
        acc[am][bn] = __builtin_amdgcn_mfma_f32_16x16x32_bf16(afr[am], bfr[bn], acc[am][bn], 0, 0, 0);
    __builtin_amdgcn_s_setprio(0);
  };

  // one K-tile, staging tile kt_far into (fA,fB); vmcnt(6) boundary
  auto step_full = [&](const u16* cA, const u16* cB, u16* fA, u16* fB, int kt_far) {
    short8 a0[4], b0[4];
    dsread(cA, cB, 0, a0, b0);
    stageA2(fA, kt_far, 0);
    stageB1(fB, kt_far, 0);
    __builtin_amdgcn_s_barrier();
    asm volatile("s_waitcnt lgkmcnt(0)" ::: "memory");
    __builtin_amdgcn_sched_barrier(0);
    mfma16(a0, b0);
    __builtin_amdgcn_s_barrier();
    short8 a1[4], b1[4];
    dsread(cA, cB, 1, a1, b1);
    stageA2(fA, kt_far, 2);
    stageB1(fB, kt_far, 1);
    __builtin_amdgcn_s_barrier();
    asm volatile("s_waitcnt lgkmcnt(0)" ::: "memory");
    __builtin_amdgcn_sched_barrier(0);
    mfma16(a1, b1);
    asm volatile("s_waitcnt vmcnt(6)" ::: "memory");
    __builtin_amdgcn_s_barrier();
  };
  // tail K-tile: no staging; endv: 0 -> vmcnt(0)+barrier, -1 -> nothing
  auto step_tail = [&](const u16* cA, const u16* cB, int endv) {
    short8 a0[4], b0[4];
    dsread(cA, cB, 0, a0, b0);
    __builtin_amdgcn_s_barrier();
    asm volatile("s_waitcnt lgkmcnt(0)" ::: "memory");
    __builtin_amdgcn_sched_barrier(0);
    mfma16(a0, b0);
    __builtin_amdgcn_s_barrier();
    short8 a1[4], b1[4];
    dsread(cA, cB, 1, a1, b1);
    asm volatile("s_waitcnt lgkmcnt(0)" ::: "memory");
    __builtin_amdgcn_sched_barrier(0);
    mfma16(a1, b1);
    if (endv == 0) {
      asm volatile("s_waitcnt vmcnt(0)" ::: "memory");
      __builtin_amdgcn_s_barrier();
    }
  };

  // prologue: stage tiles 0,1
  stageA2(LA0, 0, 0); stageA2(LA0, 0, 2); stageB1(LB0, 0, 0); stageB1(LB0, 0, 1);
  stageA2(LA1, 1, 0); stageA2(LA1, 1, 2); stageB1(LB1, 1, 0); stageB1(LB1, 1, 1);
  asm volatile("s_waitcnt vmcnt(6)" ::: "memory");   // tile 0 landed
  __builtin_amdgcn_s_barrier();

  // main: tiles 0..20 (7 triples), each stages t+2
  for (int j = 0; j < 7; j++) {
    int kt = 3 * j;
    step_full(LA0, LB0, LA2, LB2, kt + 2);
    step_full(LA1, LB1, LA0, LB0, kt + 3);
    step_full(LA2, LB2, LA1, LB1, kt + 4);
  }
  // peeled tail: t=21 (stages 23), t=22 (drain), t=23 (last)
  step_full(LA0, LB0, LA2, LB2, 23);
  step_tail(LA1, LB1, 0);
  step_tail(LA2, LB2, -1);

#pragma unroll
  for (int bn = 0; bn < 4; bn++) {
    int o = bn0 + wc * 64 + bn * 16 + l15;
    float bv = bias[o];
    float psum = 0.f, psq = 0.f;
#pragma unroll
    for (int am = 0; am < 4; am++) {
#pragma unroll
      for (int r = 0; r < 4; r++) {
        int s = bm0 + wr * 64 + am * 16 + l4 * 4 + r;
        float v = acc[am][bn][r] + bv;
        v = (s < len) ? v : 0.f;
        size_t off = ((size_t)(b * SS + s)) * HH + o;
        if (fout) {
          fout[off] = (v + resid[off]) * 0.70710678118654752f;
        } else {
          yout[off] = f2bf(v);
          psum += v;
          psq += v * v;
        }
      }
    }
    if (sum) {
      // masked rows contribute exactly 0; reduce over the 4 l4 lanes
      psum += __shfl_xor(psum, 16, 64);
      psum += __shfl_xor(psum, 32, 64);
      psq  += __shfl_xor(psq, 16, 64);
      psq  += __shfl_xor(psq, 32, 64);
      if (l4 == 0) {
        atomicAdd(&sum[b * HH + o], psum);
        atomicAdd(&sumsq[b * HH + o], psq);
      }
    }
  }
}

extern "C" void kernel_launch(void* const* d_in, const int* in_sizes, int n_in,
                              void* d_out, int out_size, void* d_ws, size_t ws_size,
                              hipStream_t stream) {
  const float* x    = (const float*)d_in[0];
  const float* sty  = (const float*)d_in[1];
  const int*   lens = (const int*)d_in[2];
  const float* p1w  = (const float*)d_in[3];
  const float* p1b  = (const float*)d_in[4];
  const float* p2w  = (const float*)d_in[5];
  const float* p2b  = (const float*)d_in[6];
  const float* c1v  = (const float*)d_in[7];
  const float* c1g  = (const float*)d_in[8];
  const float* c1b  = (const float*)d_in[9];
  const float* c2v  = (const float*)d_in[10];
  const float* c2g  = (const float*)d_in[11];
  const float* c2b  = (const float*)d_in[12];
  float* out = (float*)d_out;

  char* ws = (char*)d_ws;
  size_t cur = 0;
  auto alloc = [&](size_t bytes) {
    void* p = ws + cur;
    cur += (bytes + 255) & ~(size_t)255;
    return p;
  };
  u16*   wt1  = (u16*)alloc((size_t)3 * HH * HH * 2);
  u16*   wt2  = (u16*)alloc((size_t)3 * HH * HH * 2);
  float* g1   = (float*)alloc(NB * HH * 4);
  float* be1  = (float*)alloc(NB * HH * 4);
  float* g2   = (float*)alloc(NB * HH * 4);
  float* be2  = (float*)alloc(NB * HH * 4);
  float* sum1 = (float*)alloc(NB * HH * 4);
  float* sq1  = (float*)alloc(NB * HH * 4);
  float* sum2 = (float*)alloc(NB * HH * 4);
  float* sq2  = (float*)alloc(NB * HH * 4);
  float* a1   = (float*)alloc(NB * HH * 4);
  float* c1   = (float*)alloc(NB * HH * 4);
  float* a2   = (float*)alloc(NB * HH * 4);
  float* c2   = (float*)alloc(NB * HH * 4);
  u16*   z1   = (u16*)alloc((size_t)NB * SP * HH * 2);
  u16*   y1   = (u16*)alloc((size_t)NB * SS * HH * 2);
  u16*   z2   = (u16*)alloc((size_t)NB * SP * HH * 2);

  // zero the 4 stats arrays (contiguous: sum1,sq1,sum2,sq2)
  k_zero<<<(4 * NB * HH + 255) / 256, 256, 0, stream>>>(sum1, 4 * NB * HH);

  // style projections (both)
  k_proj<<<(2 * NB * 2 * HH + 255) / 256, 256, 0, stream>>>(sty, p1w, p1b, p2w, p2b,
                                                            g1, be1, g2, be2);
  // weight norm + bf16 repack (both convs)
  k_wnorm<<<2 * HH, 256, 0, stream>>>(c1v, c1g, c2v, c2g, wt1, wt2);

  // stage 1 stats over x
  k_stats_f32<<<NB * (HH / 256) * 16, 256, 0, stream>>>(x, lens, sum1, sq1);
  k_fin<<<(NB * HH + 255) / 256, 256, 0, stream>>>(sum1, sq1, lens, g1, be1, a1, c1);

  // z1 = mask * lrelu(adain1(x))
  {
    long n = (long)NB * SP * HH / 4;
    k_prep_f32<<<(int)((n + 255) / 256), 256, 0, stream>>>(x, a1, c1, lens, z1);
  }
  // y1 = (conv1(z1) + b1) * mask (bf16), with fused stage-2 stats
  k_conv<<<NB * (SS / BM) * (HH / BN), 512, 0, stream>>>(z1, wt1, c1b, lens, y1,
                                                          nullptr, nullptr, sum2, sq2);

  k_fin<<<(NB * HH + 255) / 256, 256, 0, stream>>>(sum2, sq2, lens, g2, be2, a2, c2);

  // z2 = mask * lrelu(adain2(y1))
  {
    long n = (long)NB * SP * HH / 4;
    k_prep_bf16<<<(int)((n + 255) / 256), 256, 0, stream>>>(y1, a2, c2, lens, z2);
  }
  // out = ((conv2(z2) + b2) * mask + x) / sqrt(2)
  k_conv<<<NB * (SS / BM) * (HH / BN), 512, 0, stream>>>(z2, wt2, c2b, lens, nullptr,
                                                          x, out, nullptr, nullptr);
}

// Round 6
// 146.760 us; speedup vs baseline: 1.0555x; 1.0555x over previous
//
#include <hip/hip_runtime.h>

#define NB 8
#define SS 2048
#define HH 512
#define NSTY 128
#define SP (SS + 2)
#define EPSF 1e-5f

#define BM 256
#define BN 128
#define BKI 32          // i-chunk (per-tap K step); effective K per step = 3*32

typedef __attribute__((ext_vector_type(8))) short short8;
typedef __attribute__((ext_vector_type(4))) float floatx4;
typedef __attribute__((ext_vector_type(4))) unsigned short u16x4;
typedef unsigned short u16;

__device__ __forceinline__ float bf2f(u16 u) {
  union { float f; unsigned int i; } v; v.i = ((unsigned int)u) << 16; return v.f;
}
__device__ __forceinline__ u16 f2bf(float f) {
  union { float f; unsigned int i; } v; v.f = f;
  unsigned int x = v.i;
  return (u16)((x + 0x7fffu + ((x >> 16) & 1u)) >> 16);
}
__device__ __forceinline__ float lrelu(float v) { return v >= 0.f ? v : 0.2f * v; }
__device__ __forceinline__ int f4(int r) { return (r ^ (r >> 2)) & 3; }  // slot swizzle

__device__ __forceinline__ void gld_lds16(const u16* g, u16* l) {
  __builtin_amdgcn_global_load_lds((const __attribute__((address_space(1))) void*)g,
                                   (__attribute__((address_space(3))) void*)l, 16, 0, 0);
}

// ---------------- zero stats ----------------
__global__ void k_zero(float* p, int n) {
  int i = blockIdx.x * 256 + threadIdx.x;
  if (i < n) p[i] = 0.f;
}

// ---------------- style projections (both) ----------------
__global__ void k_proj(const float* style, const float* w1, const float* b1,
                       const float* w2, const float* b2,
                       float* g1, float* be1, float* g2, float* be2) {
  int idx = blockIdx.x * 256 + threadIdx.x;         // 2 * NB * 2H
  if (idx >= 2 * NB * 2 * HH) return;
  int which = idx / (NB * 2 * HH);
  int r = idx % (NB * 2 * HH);
  int b = r / (2 * HH);
  int j = r % (2 * HH);
  const float* w = which ? w2 : w1;
  const float* bias = which ? b2 : b1;
  float acc = bias[j];
  const float* st = style + b * NSTY;
  const float* wr = w + j * NSTY;
  for (int t = 0; t < NSTY; t++) acc += st[t] * wr[t];
  float* gd = which ? g2 : g1;
  float* bd = which ? be2 : be1;
  if (j < HH) gd[b * HH + j] = acc;
  else        bd[b * HH + (j - HH)] = acc;
}

// ---------------- weight norm + repack to bf16 [k][o][i] ----------------
__global__ void k_wnorm(const float* v1, const float* g1, const float* v2, const float* g2,
                        u16* wt1, u16* wt2) {
  int o = blockIdx.x % HH;
  int which = blockIdx.x / HH;
  const float* v = which ? v2 : v1;
  const float* g = which ? g2 : g1;
  u16* wt = which ? wt2 : wt1;
  float s = 0.f;
  for (int e = threadIdx.x; e < HH * 3; e += 256) {
    float x = v[o * HH * 3 + e];
    s += x * x;
  }
  for (int off = 32; off > 0; off >>= 1) s += __shfl_down(s, off, 64);
  __shared__ float red[4];
  int wid = threadIdx.x >> 6, lane = threadIdx.x & 63;
  if (lane == 0) red[wid] = s;
  __syncthreads();
  float tot = red[0] + red[1] + red[2] + red[3];
  float scale = g[o] / sqrtf(tot);
  for (int e = threadIdx.x; e < HH * 3; e += 256) {
    int i = e / 3, k = e % 3;      // v[o][i][k] flat = o*1536 + e
    wt[(k * HH + o) * HH + i] = f2bf(v[o * HH * 3 + e] * scale);
  }
}

// ---------------- masked stats over S (f32 input) ----------------
__global__ void k_stats_f32(const float* x, const int* lens, float* sum, float* sumsq) {
  const int SSPLIT = 16;
  int t = blockIdx.x;
  int sc = t % SSPLIT; t /= SSPLIT;
  int ht = t % (HH / 256); t /= (HH / 256);
  int b = t;
  int h = ht * 256 + threadIdx.x;
  int len = lens[b];
  int s0 = sc * (SS / SSPLIT);
  int se = min(s0 + SS / SSPLIT, len);
  float sm = 0.f, sq = 0.f;
  for (int s = s0; s < se; s++) {
    float v = x[(b * SS + s) * HH + h];
    sm += v; sq += v * v;
  }
  if (se > s0) {
    atomicAdd(&sum[b * HH + h], sm);
    atomicAdd(&sumsq[b * HH + h], sq);
  }
}

// ---------------- finalize adain affine ----------------
__global__ void k_fin(const float* sum, const float* sumsq, const int* lens,
                      const float* gam, const float* bet, float* a, float* c) {
  int idx = blockIdx.x * 256 + threadIdx.x;   // NB*HH
  if (idx >= NB * HH) return;
  int b = idx / HH;
  float cnt = (float)lens[b];
  float mean = sum[idx] / cnt;
  float var = sumsq[idx] / cnt - mean * mean;
  float rs = rsqrtf(var + EPSF);
  float av = (1.f + gam[idx]) * rs;
  a[idx] = av;
  c[idx] = bet[idx] - mean * av;
}

// ---------------- Z prep (f32 src), XCD-aligned: XCD b owns batch b ----------
// grid = NB * 1025 = 8200 (exact); bid%8 = batch so batch b's z lands in
// XCD b's L2 (matching k_conv's XCD remap -> staging reads hit local L2).
__global__ void k_prep_f32(const float* x, const float* a, const float* c,
                           const int* lens, u16* z) {
  int b = blockIdx.x & 7;
  int v = (blockIdx.x >> 3) * 256 + threadIdx.x;   // 0..262399 (exact)
  long off = (long)v * 4;                          // elem offset within batch
  int i = (int)(off % HH);
  int r = (int)(off / HH);                         // 0..SP-1
  int s = r - 1;
  u16x4 outv;
  if (s < 0 || s >= SS || s >= lens[b]) {
    outv = (u16x4){0, 0, 0, 0};
  } else {
    const float4 xv = *(const float4*)(x + ((long)(b * SS + s)) * HH + i);
    const float4 av = *(const float4*)(a + b * HH + i);
    const float4 cv = *(const float4*)(c + b * HH + i);
    outv.x = f2bf(lrelu(av.x * xv.x + cv.x));
    outv.y = f2bf(lrelu(av.y * xv.y + cv.y));
    outv.z = f2bf(lrelu(av.z * xv.z + cv.z));
    outv.w = f2bf(lrelu(av.w * xv.w + cv.w));
  }
  *(u16x4*)(z + ((long)(b * SP + r)) * HH + i) = outv;
}

// ---------------- Z prep (bf16 src), XCD-aligned ----------------
__global__ void k_prep_bf16(const u16* y, const float* a, const float* c,
                            const int* lens, u16* z) {
  int b = blockIdx.x & 7;
  int v = (blockIdx.x >> 3) * 256 + threadIdx.x;
  long off = (long)v * 4;
  int i = (int)(off % HH);
  int r = (int)(off / HH);
  int s = r - 1;
  u16x4 outv;
  if (s < 0 || s >= SS || s >= lens[b]) {
    outv = (u16x4){0, 0, 0, 0};
  } else {
    const u16x4 yv = *(const u16x4*)(y + ((long)(b * SS + s)) * HH + i);
    const float4 av = *(const float4*)(a + b * HH + i);
    const float4 cv = *(const float4*)(c + b * HH + i);
    outv.x = f2bf(lrelu(av.x * bf2f(yv.x) + cv.x));
    outv.y = f2bf(lrelu(av.y * bf2f(yv.y) + cv.y));
    outv.z = f2bf(lrelu(av.z * bf2f(yv.z) + cv.z));
    outv.w = f2bf(lrelu(av.w * bf2f(yv.w) + cv.w));
  }
  *(u16x4*)(z + ((long)(b * SP + r)) * HH + i) = outv;
}

// ---------------- conv1d: tap-shared z-panel GEMM ----------------
// KEY CHANGE vs flat-GEMM: the 3 taps' A-tiles are row-shifted copies of the
// same z rows. Stage the z panel ONCE per ic-chunk ([272 rows][32 cols], rows
// bm0..bm0+257 used) and read the 3 taps from shifted LDS rows -> A staging
// drops 3x. Total staging traffic 302 MB -> 168 MB (the measured ~5 TB/s
// staging-path invariant across R1-R5 is the bottleneck).
// BM=256 BN=128, 512 threads (8 waves 4Mx2N, wave tile 64x64, acc 4x4).
// 16 ic-steps; per step per wave: 3 taps x (8 ds_read_b128 + 16 MFMA).
// 3-buffer ring (123 KB), 2-deep prefetch, uniform 6 gld/wave/step
// (A 2 + panel-tail 1 dup'd by all waves + B 3) -> counted vmcnt(6), never 0
// in main loop. Slot swizzle: slot ^= (r^(r>>2))&3 on BOTH global source col
// and ds_read addr (involution, rule 21). XCD remap: one batch per XCD,
// matching k_prep's writer XCD -> z staged from LOCAL L2.
#define A_U16 (272 * 32)          // 8704
#define B_U16 (3 * 128 * 32)      // 12288
#define BUF_U16 (A_U16 + B_U16)   // 20992 (41 KB higher..), 3 bufs = 123 KB

__global__ __launch_bounds__(512) void k_conv(const u16* __restrict__ z,
                                              const u16* __restrict__ wt,
                                              const float* __restrict__ bias,
                                              const int* __restrict__ lens,
                                              u16* __restrict__ yout,
                                              const float* __restrict__ resid,
                                              float* __restrict__ fout,
                                              float* __restrict__ sum,
                                              float* __restrict__ sumsq) {
  __shared__ __align__(16) u16 L0[BUF_U16];
  __shared__ __align__(16) u16 L1[BUF_U16];
  __shared__ __align__(16) u16 L2[BUF_U16];

  int nwg = gridDim.x;                        // 256, divisible by 8
  int bid = blockIdx.x;
  int t = (bid & 7) * (nwg >> 3) + (bid >> 3);     // XCD-contiguous logical id
  int bn0 = (t % (HH / BN)) * BN; t /= (HH / BN);
  int bm0 = (t % (SS / BM)) * BM; t /= (SS / BM);
  int b = t;

  int tid = threadIdx.x;
  int wave = tid >> 6, lane = tid & 63;
  int wr = wave >> 1, wc = wave & 1;          // 4 M-waves x 2 N-waves
  int l15 = lane & 15, l4 = lane >> 4;
  int lrow = lane >> 2, lslot = lane & 3;     // staging: 16 rows x 4 slots/instr

  const u16* zb = z + (size_t)b * SP * HH;
  int len = lens[b];

  floatx4 acc[4][4] = {};

  // stage ic-chunk kt into buffer S: z panel rows 0..271 (bm0-relative) at
  // S[0..A_U16), weights [3][128][32] at S[A_U16..). 6 gld/wave, uniform.
  auto stage = [&](u16* S, int kt) {
    int ic = kt * BKI;
    // A: 2 full instrs/wave (rows wave*32 + i*16 + lrow)
#pragma unroll
    for (int i = 0; i < 2; i++) {
      int p = wave * 32 + i * 16 + lrow;               // panel row < 256
      int col = ic + ((lslot ^ f4(p)) * 8);
      gld_lds16(zb + (size_t)(bm0 + p) * HH + col,
                S + wave * 1024 + i * 512 + lane * 8);
    }
    // panel tail rows 256..271 (only 256..257 consumed): ALL waves issue the
    // same 1KB write (identical data, benign dup) -> uniform vmcnt
    {
      int p = 256 + lrow;
      int zr = bm0 + p; if (zr > SP - 1) zr = SP - 1;  // clamp (rows >257 unused)
      int col = ic + ((lslot ^ f4(p)) * 8);
      gld_lds16(zb + (size_t)zr * HH + col, S + 8192 + lane * 8);
    }
    // B: 3 instrs/wave over lds rows rb = tap*128 + o_local (384 rows)
#pragma unroll
    for (int i = 0; i < 3; i++) {
      int rb = wave * 48 + i * 16 + lrow;
      int tap = rb >> 7, o = rb & 127;
      int col = ic + ((lslot ^ f4(rb)) * 8);
      gld_lds16(wt + (size_t)tap * HH * HH + (size_t)(bn0 + o) * HH + col,
                S + A_U16 + wave * 1536 + i * 512 + lane * 8);
    }
  };

  auto compute = [&](const u16* S) {
    const u16* sA = S;
    const u16* sB = S + A_U16;
#pragma unroll
    for (int tap = 0; tap < 3; tap++) {
      short8 afr[4], bfr[4];
#pragma unroll
      for (int am = 0; am < 4; am++) {
        int ar = wr * 64 + am * 16 + l15 + tap;        // shifted panel row
        afr[am] = *(const short8*)&sA[ar * 32 + ((l4 ^ f4(ar)) * 8)];
      }
#pragma unroll
      for (int j = 0; j < 4; j++) {
        int br = tap * 128 + wc * 64 + j * 16 + l15;
        bfr[j] = *(const short8*)&sB[br * 32 + ((l4 ^ f4(br)) * 8)];
      }
      __builtin_amdgcn_s_setprio(1);
#pragma unroll
      for (int am = 0; am < 4; am++)
#pragma unroll
        for (int bn = 0; bn < 4; bn++)
          acc[am][bn] = __builtin_amdgcn_mfma_f32_16x16x32_bf16(afr[am], bfr[bn], acc[am][bn], 0, 0, 0);
      __builtin_amdgcn_s_setprio(0);
    }
  };

#define STEP(CUR, DST, KT)                                  \
  stage(DST, KT);                                           \
  compute(CUR);                                             \
  asm volatile("s_waitcnt vmcnt(6)" ::: "memory");          \
  __builtin_amdgcn_s_barrier();

  // prologue: 2-deep
  stage(L0, 0);
  stage(L1, 1);
  asm volatile("s_waitcnt vmcnt(6)" ::: "memory");   // chunk 0 landed
  __builtin_amdgcn_s_barrier();

  // 16 ic-steps; main 14 with 2-deep prefetch (ring unrolled in triples)
  for (int j = 0; j < 4; j++) {                      // steps 0..11
    STEP(L0, L2, 3 * j + 2)
    STEP(L1, L0, 3 * j + 3)
    STEP(L2, L1, 3 * j + 4)
  }
  STEP(L0, L2, 14)                                   // step 12
  STEP(L1, L0, 15)                                   // step 13
  compute(L2);                                       // step 14 (landed)
  asm volatile("s_waitcnt vmcnt(0)" ::: "memory");
  __builtin_amdgcn_s_barrier();
  compute(L0);                                       // step 15
#undef STEP

#pragma unroll
  for (int bn = 0; bn < 4; bn++) {
    int o = bn0 + wc * 64 + bn * 16 + l15;
    float bv = bias[o];
    float psum = 0.f, psq = 0.f;
#pragma unroll
    for (int am = 0; am < 4; am++) {
#pragma unroll
      for (int r = 0; r < 4; r++) {
        int s = bm0 + wr * 64 + am * 16 + l4 * 4 + r;
        float v = acc[am][bn][r] + bv;
        v = (s < len) ? v : 0.f;
        size_t off = ((size_t)(b * SS + s)) * HH + o;
        if (fout) {
          fout[off] = (v + resid[off]) * 0.70710678118654752f;
        } else {
          yout[off] = f2bf(v);
          psum += v;
          psq += v * v;
        }
      }
    }
    if (sum) {
      // masked rows contribute exactly 0; reduce over the 4 l4 lanes
      psum += __shfl_xor(psum, 16, 64);
      psum += __shfl_xor(psum, 32, 64);
      psq  += __shfl_xor(psq, 16, 64);
      psq  += __shfl_xor(psq, 32, 64);
      if (l4 == 0) {
        atomicAdd(&sum[b * HH + o], psum);
        atomicAdd(&sumsq[b * HH + o], psq);
      }
    }
  }
}

extern "C" void kernel_launch(void* const* d_in, const int* in_sizes, int n_in,
                              void* d_out, int out_size, void* d_ws, size_t ws_size,
                              hipStream_t stream) {
  const float* x    = (const float*)d_in[0];
  const float* sty  = (const float*)d_in[1];
  const int*   lens = (const int*)d_in[2];
  const float* p1w  = (const float*)d_in[3];
  const float* p1b  = (const float*)d_in[4];
  const float* p2w  = (const float*)d_in[5];
  const float* p2b  = (const float*)d_in[6];
  const float* c1v  = (const float*)d_in[7];
  const float* c1g  = (const float*)d_in[8];
  const float* c1b  = (const float*)d_in[9];
  const float* c2v  = (const float*)d_in[10];
  const float* c2g  = (const float*)d_in[11];
  const float* c2b  = (const float*)d_in[12];
  float* out = (float*)d_out;

  char* ws = (char*)d_ws;
  size_t cur = 0;
  auto alloc = [&](size_t bytes) {
    void* p = ws + cur;
    cur += (bytes + 255) & ~(size_t)255;
    return p;
  };
  u16*   wt1  = (u16*)alloc((size_t)3 * HH * HH * 2);
  u16*   wt2  = (u16*)alloc((size_t)3 * HH * HH * 2);
  float* g1   = (float*)alloc(NB * HH * 4);
  float* be1  = (float*)alloc(NB * HH * 4);
  float* g2   = (float*)alloc(NB * HH * 4);
  float* be2  = (float*)alloc(NB * HH * 4);
  float* sum1 = (float*)alloc(NB * HH * 4);
  float* sq1  = (float*)alloc(NB * HH * 4);
  float* sum2 = (float*)alloc(NB * HH * 4);
  float* sq2  = (float*)alloc(NB * HH * 4);
  float* a1   = (float*)alloc(NB * HH * 4);
  float* c1   = (float*)alloc(NB * HH * 4);
  float* a2   = (float*)alloc(NB * HH * 4);
  float* c2   = (float*)alloc(NB * HH * 4);
  u16*   z1   = (u16*)alloc((size_t)NB * SP * HH * 2);
  u16*   y1   = (u16*)alloc((size_t)NB * SS * HH * 2);
  u16*   z2   = (u16*)alloc((size_t)NB * SP * HH * 2);

  // zero the 4 stats arrays (contiguous: sum1,sq1,sum2,sq2)
  k_zero<<<(4 * NB * HH + 255) / 256, 256, 0, stream>>>(sum1, 4 * NB * HH);

  // style projections (both)
  k_proj<<<(2 * NB * 2 * HH + 255) / 256, 256, 0, stream>>>(sty, p1w, p1b, p2w, p2b,
                                                            g1, be1, g2, be2);
  // weight norm + bf16 repack (both convs)
  k_wnorm<<<2 * HH, 256, 0, stream>>>(c1v, c1g, c2v, c2g, wt1, wt2);

  // stage 1 stats over x
  k_stats_f32<<<NB * (HH / 256) * 16, 256, 0, stream>>>(x, lens, sum1, sq1);
  k_fin<<<(NB * HH + 255) / 256, 256, 0, stream>>>(sum1, sq1, lens, g1, be1, a1, c1);

  // z1 = mask * lrelu(adain1(x)); grid = NB * (SP*HH/4/256) = 8200 exact
  k_prep_f32<<<NB * (SP * HH / 4 / 256), 256, 0, stream>>>(x, a1, c1, lens, z1);

  // y1 = (conv1(z1) + b1) * mask (bf16), with fused stage-2 stats
  k_conv<<<NB * (SS / BM) * (HH / BN), 512, 0, stream>>>(z1, wt1, c1b, lens, y1,
                                                          nullptr, nullptr, sum2, sq2);

  k_fin<<<(NB * HH + 255) / 256, 256, 0, stream>>>(sum2, sq2, lens, g2, be2, a2, c2);

  // z2 = mask * lrelu(adain2(y1))
  k_prep_bf16<<<NB * (SP * HH / 4 / 256), 256, 0, stream>>>(y1, a2, c2, lens, z2);

  // out = ((conv2(z2) + b2) * mask + x) / sqrt(2)
  k_conv<<<NB * (SS / BM) * (HH / BN), 512, 0, stream>>>(z2, wt2, c2b, lens, nullptr,
                                                          x, out, nullptr, nullptr);
}